// Round 9
// baseline (1169.474 us; speedup 1.0000x reference)
//
#include <hip/hip_runtime.h>
#include <math.h>

#define NN 50000
#define MM 800000
#define HH 64

typedef short bf16x8 __attribute__((ext_vector_type(8)));
typedef float f32x4  __attribute__((ext_vector_type(4)));

// per-wave LDS fence: all LDS regions are wave-private; lockstep + lgkmcnt
// drain replaces __syncthreads
#define WFENCE() asm volatile("s_waitcnt lgkmcnt(0)" ::: "memory")

__device__ __forceinline__ float silu_f(float v) {
    return v * __builtin_amdgcn_rcpf(1.0f + __expf(-v));
}
// round-half-up fp32 -> bf16 bits (0.5 ulp max)
__device__ __forceinline__ unsigned short bfb(float a) {
    return (unsigned short)((__float_as_uint(a) + 0x8000u) >> 16);
}
// pack two f32 -> bf16x2 via v_perm
__device__ __forceinline__ unsigned pk2(float a, float b) {
    return __builtin_amdgcn_perm(__float_as_uint(b) + 0x8000u,
                                 __float_as_uint(a) + 0x8000u, 0x07060302u);
}
__device__ __forceinline__ float b2f(unsigned short s) {
    return __uint_as_float((unsigned)s << 16);
}

// ---------------- CSR build ----------------
__global__ __launch_bounds__(256) void hist_kernel(const int* __restrict__ row,
                                                   int* __restrict__ deg) {
    const int e = blockIdx.x * 256 + threadIdx.x;
    atomicAdd(&deg[row[e]], 1);
}

__global__ __launch_bounds__(1024) void scan_kernel(const int* __restrict__ deg,
                                                    int* __restrict__ rowptr,
                                                    int* __restrict__ cur) {
    __shared__ int ps[1024];
    const int t = threadIdx.x;
    const int C = (NN + 1023) / 1024;              // 49
    const int lo = t * C, hi = (lo + C < NN) ? lo + C : NN;
    int s = 0;
    for (int i = lo; i < hi; ++i) s += deg[i];
    ps[t] = s;
    __syncthreads();
    for (int off = 1; off < 1024; off <<= 1) {
        const int v = (t >= off) ? ps[t - off] : 0;
        __syncthreads();
        ps[t] += v;
        __syncthreads();
    }
    int run = ps[t] - s;                            // exclusive prefix
    for (int i = lo; i < hi; ++i) {
        rowptr[i] = run; cur[i] = run; run += deg[i];
    }
    if (t == 1023) rowptr[NN] = MM;
}

// pass A: counting-sort positions; scatter only 4B perm
__global__ __launch_bounds__(256) void fillA_kernel(
    const int* __restrict__ row, int* __restrict__ cur,
    int* __restrict__ perm)
{
    const int e = blockIdx.x * 256 + threadIdx.x;
    const int pos = atomicAdd(&cur[row[e]], 1);
    perm[pos] = e;
}

// pass B: coalesced materialize of cs/efs (random reads, sequential writes)
__global__ __launch_bounds__(256) void fillB_kernel(
    const int* __restrict__ perm, const int* __restrict__ col,
    const float* __restrict__ efea,
    int* __restrict__ cs, unsigned short* __restrict__ efs)
{
    const int p = blockIdx.x * 256 + threadIdx.x;
    const int e = perm[p];
    cs[p] = col[e];
    const float4* ef = (const float4*)(efea + (size_t)e * 8);
    const float4 e0 = ef[0], e1 = ef[1];
    uint4 ue = { pk2(e0.x, e0.y), pk2(e0.z, e0.w), pk2(e1.x, e1.y), pk2(e1.z, e1.w) };
    *(uint4*)(efs + (size_t)p * 8) = ue;
}

// ---------------- weight pre-swizzle into MFMA B-fragment layout (bf16) ----
// per layer (30720 shorts): eW1b@0 (10240), eW2b@10240, cW1b@14336,
// nW1b@18432 (8192), nW2b@26624
__global__ __launch_bounds__(256) void prep_kernel(
    const float* __restrict__ eW1, const float* __restrict__ eW2,
    const float* __restrict__ cW1, const float* __restrict__ nW1,
    const float* __restrict__ nW2, unsigned short* __restrict__ wsW)
{
    const int i = blockIdx.x * 256 + threadIdx.x;     // 0 .. 61439
    const int layer = i / 30720;
    const int rem = i - layer * 30720;
    float val;
    if (rem < 10240) {
        const int j = rem & 7, lane = (rem >> 3) & 63, nt = (rem >> 9) & 3, s = rem >> 11;
        const int kp = s * 32 + ((lane >> 4) << 3) + j;
        const int n  = nt * 16 + (lane & 15);
        if (kp > 136) val = 0.0f;
        else {
            const int k = (kp == 136) ? 0 : kp + 1;   // k'=136 is the r2 row (orig k=0)
            val = eW1[layer * 137 * 64 + k * 64 + n];
        }
    } else if (rem < 14336) {
        const int r2 = rem - 10240;
        const int j = r2 & 7, lane = (r2 >> 3) & 63, nt = (r2 >> 9) & 3, s = r2 >> 11;
        val = eW2[layer * 4096 + (s * 32 + ((lane >> 4) << 3) + j) * 64 + nt * 16 + (lane & 15)];
    } else if (rem < 18432) {
        const int r3 = rem - 14336;
        const int j = r3 & 7, lane = (r3 >> 3) & 63, nt = (r3 >> 9) & 3, s = r3 >> 11;
        val = cW1[layer * 4096 + (s * 32 + ((lane >> 4) << 3) + j) * 64 + nt * 16 + (lane & 15)];
    } else if (rem < 26624) {
        const int r4 = rem - 18432;
        const int j = r4 & 7, lane = (r4 >> 3) & 63, nt = (r4 >> 9) & 3, s = r4 >> 11;
        const int kp = s * 32 + ((lane >> 4) << 3) + j;      // < 128
        val = nW1[layer * 8192 + kp * 64 + nt * 16 + (lane & 15)];
    } else {
        const int r5 = rem - 26624;
        const int j = r5 & 7, lane = (r5 >> 3) & 63, nt = (r5 >> 9) & 3, s = r5 >> 11;
        val = nW2[layer * 4096 + (s * 32 + ((lane >> 4) << 3) + j) * 64 + nt * 16 + (lane & 15)];
    }
    wsW[i] = bfb(val);
}

// ---------------- embedding: fp32 h + bf16 mirror ----------------
__global__ __launch_bounds__(256) void embed_kernel(
    const float* __restrict__ h_in, const float* __restrict__ W,
    const float* __restrict__ b, float* __restrict__ h_out,
    unsigned short* __restrict__ hb)
{
    const int idx = blockIdx.x * 256 + threadIdx.x;
    const int n = idx >> 6, j = idx & 63;
    float acc = b[j];
    #pragma unroll
    for (int k = 0; k < 16; ++k)
        acc += h_in[n * 16 + k] * W[k * HH + j];
    h_out[idx] = acc;
    hb[idx] = bfb(acc);
}

// ---------------- MFMA edge kernel: ONE WAVE PER ROW ----------------
// Wave owns row n; loops over ceil(deg/16) chunks of 16 edges (last edge
// duplicated for padding, masked at MS write). Accumulates tmsg + f in
// registers; plain stores (no atomics, no memsets). x-update fused:
// reads x_cur, writes x_next.
__global__ __launch_bounds__(256, 6) void edge_mfma_kernel(
    const float* __restrict__ x_cur, float* __restrict__ x_next,
    const unsigned short* __restrict__ hb,
    const int* __restrict__ cs, const unsigned short* __restrict__ efs,
    const int* __restrict__ rowptr,
    const unsigned short* __restrict__ w1b, const unsigned short* __restrict__ w2b,
    const unsigned short* __restrict__ cw1b,
    const float* __restrict__ b1, const float* __restrict__ b2,
    const float* __restrict__ cb1, const float* __restrict__ cw2,
    const float* __restrict__ cb2,
    unsigned short* __restrict__ tmsgb)
{
    __shared__ __align__(16) unsigned short S[4][16][168];
    __shared__ float RV[4][16][4];

    const int tid = threadIdx.x;
    const int w = tid >> 6, lane = tid & 63;
    const int l15 = lane & 15, quad = lane >> 4;
    const int le = lane >> 2, sub = lane & 3;
    const int n = blockIdx.x * 4 + w;          // this wave's row (grid 12500)

    float b1v[4], b2v[4], cb1v[4], cw2v[4];
    #pragma unroll
    for (int nt = 0; nt < 4; ++nt) {
        b1v[nt]  = b1[nt * 16 + l15];
        b2v[nt]  = b2[nt * 16 + l15];
        cb1v[nt] = cb1[nt * 16 + l15];
        cw2v[nt] = cw2[nt * 16 + l15];
    }
    const float cb2s = cb2[0];

    {   // zero the K-pad [138,160) once
        unsigned short* Sr = &S[w][le][0];
        if (sub == 0) {
            *(unsigned*)&Sr[138] = 0u; *(unsigned*)&Sr[140] = 0u; *(unsigned*)&Sr[142] = 0u;
        } else if (sub == 1) {
            *(unsigned*)&Sr[144] = 0u; *(unsigned*)&Sr[146] = 0u;
            *(unsigned*)&Sr[148] = 0u; *(unsigned*)&Sr[150] = 0u;
        } else if (sub == 2) {
            *(unsigned*)&Sr[152] = 0u; *(unsigned*)&Sr[154] = 0u;
            *(unsigned*)&Sr[156] = 0u; *(unsigned*)&Sr[158] = 0u;
        }
    }

    const int s0 = rowptr[n], s1 = rowptr[n + 1];
    const int deg = s1 - s0;
    const float xr0 = x_cur[3 * n + 0];
    const float xr1 = x_cur[3 * n + 1];
    const float xr2 = x_cur[3 * n + 2];

    float macc = 0.f;      // per-lane column sum of msg
    float facc = 0.f;      // partial f sums (lanes l15<3, per quad)
    WFENCE();

    for (int j0 = s0; j0 < s1; j0 += 16) {
        const int valid = (s1 - j0 < 16) ? (s1 - j0) : 16;
        int pe = j0 + le;
        if (pe >= s1) pe = s1 - 1;           // duplicate last edge (masked)
        const int c = cs[pe];

        // ---- gather: 4 lanes per edge ----
        unsigned short* Srow = &S[w][le][0];
        {
            const unsigned short* hr = hb + (size_t)n * HH + sub * 16;
            *(uint4*)&Srow[sub * 16]     = *(const uint4*)(hr);
            *(uint4*)&Srow[sub * 16 + 8] = *(const uint4*)(hr + 8);
            const unsigned short* hc = hb + (size_t)c * HH + sub * 16;
            *(uint4*)&Srow[64 + sub * 16]     = *(const uint4*)(hc);
            *(uint4*)&Srow[64 + sub * 16 + 8] = *(const uint4*)(hc + 8);
        }
        if (sub == 0) {
            const float rx = xr0 - x_cur[3 * c + 0];
            const float ry = xr1 - x_cur[3 * c + 1];
            const float rz = xr2 - x_cur[3 * c + 2];
            const float r2 = rx * rx + ry * ry + rz * rz;
            RV[w][le][0] = rx; RV[w][le][1] = ry; RV[w][le][2] = rz;
            *(unsigned*)&Srow[136] = (unsigned)bfb(r2);   // zeroes col 137 too
        } else if (sub == 1) {
            *(uint4*)&Srow[128] = *(const uint4*)(efs + (size_t)pe * 8);
        }
        WFENCE();

        // ---- GEMM1: S[16x160] @ W1[160x64] -> H1 (alias cols 0..63) ----
        bf16x8 af[5];
        #pragma unroll
        for (int s = 0; s < 5; ++s)
            af[s] = *(const bf16x8*)&S[w][l15][s * 32 + quad * 8];
        WFENCE();   // af in regs before H1 overwrites the same cols
        #pragma unroll
        for (int nt = 0; nt < 4; ++nt) {
            f32x4 a = {0.f, 0.f, 0.f, 0.f};
            #pragma unroll
            for (int s = 0; s < 5; ++s) {
                bf16x8 bf = *(const bf16x8*)(w1b + ((s * 4 + nt) * 64 + lane) * 8);
                a = __builtin_amdgcn_mfma_f32_16x16x32_bf16(af[s], bf, a, 0, 0, 0);
            }
            #pragma unroll
            for (int rr = 0; rr < 4; ++rr)
                S[w][quad * 4 + rr][nt * 16 + l15] = bfb(silu_f(a[rr] + b1v[nt]));
        }
        WFENCE();

        // ---- GEMM2: H1 @ W2 -> msg (masked write for padded rows) ----
        bf16x8 a2[2];
        #pragma unroll
        for (int s = 0; s < 2; ++s)
            a2[s] = *(const bf16x8*)&S[w][l15][s * 32 + quad * 8];
        WFENCE();   // a2 in regs before MS overwrites
        #pragma unroll
        for (int nt = 0; nt < 4; ++nt) {
            f32x4 m = {0.f, 0.f, 0.f, 0.f};
            #pragma unroll
            for (int s = 0; s < 2; ++s) {
                bf16x8 bf = *(const bf16x8*)(w2b + ((s * 4 + nt) * 64 + lane) * 8);
                m = __builtin_amdgcn_mfma_f32_16x16x32_bf16(a2[s], bf, m, 0, 0, 0);
            }
            #pragma unroll
            for (int rr = 0; rr < 4; ++rr) {
                const int g = quad * 4 + rr;
                const unsigned short sv =
                    (g < valid) ? bfb(silu_f(m[rr] + b2v[nt])) : (unsigned short)0;
                S[w][g][nt * 16 + l15] = sv;
            }
        }
        WFENCE();

        // ---- GEMM3 A-frags + msg column accumulate (zeros for padding) ----
        bf16x8 a3[2];
        #pragma unroll
        for (int s = 0; s < 2; ++s)
            a3[s] = *(const bf16x8*)&S[w][l15][s * 32 + quad * 8];
        #pragma unroll
        for (int g = 0; g < 16; ++g)
            macc += b2f(S[w][g][lane]);

        // ---- GEMM3: msg @ cW1 -> c1; dot cW2 -> cm; accumulate f ----
        float pr[4] = {0.f, 0.f, 0.f, 0.f};
        #pragma unroll
        for (int nt = 0; nt < 4; ++nt) {
            f32x4 q = {0.f, 0.f, 0.f, 0.f};
            #pragma unroll
            for (int s = 0; s < 2; ++s) {
                bf16x8 bf = *(const bf16x8*)(cw1b + ((s * 4 + nt) * 64 + lane) * 8);
                q = __builtin_amdgcn_mfma_f32_16x16x32_bf16(a3[s], bf, q, 0, 0, 0);
            }
            #pragma unroll
            for (int rr = 0; rr < 4; ++rr)
                pr[rr] += silu_f(q[rr] + cb1v[nt]) * cw2v[nt];
        }
        #pragma unroll
        for (int rr = 0; rr < 4; ++rr) {
            float tt = pr[rr];
            tt += __shfl_xor(tt, 1, 64);
            tt += __shfl_xor(tt, 2, 64);
            tt += __shfl_xor(tt, 4, 64);
            tt += __shfl_xor(tt, 8, 64);
            const float cm = tt + cb2s;
            const int g = quad * 4 + rr;
            if (l15 < 3 && g < valid)
                facc += RV[w][g][l15] * cm;
        }
        WFENCE();
    }

    // ---- plain stores: tmsg (bf16) + fused x update ----
    tmsgb[(size_t)n * HH + lane] = bfb(macc);
    facc += __shfl_xor(facc, 16, 64);
    facc += __shfl_xor(facc, 32, 64);
    if (quad == 0 && l15 < 3) {
        const float cn = fmaxf((float)deg, 1.0f);
        float tf = facc * __builtin_amdgcn_rcpf(cn);
        tf = fminf(fmaxf(tf, -100.0f), 100.0f);
        const float xv = (l15 == 0) ? xr0 : ((l15 == 1) ? xr1 : xr2);
        x_next[3 * n + l15] = xv + tf;
    }
}

// ---------------- MFMA node kernel: 16 nodes per wave ----------------
__global__ __launch_bounds__(256) void node_mfma_kernel(
    float* __restrict__ h, unsigned short* __restrict__ hb,
    const unsigned short* __restrict__ tmsgb,
    const unsigned short* __restrict__ nw1b, const unsigned short* __restrict__ nw2b,
    const float* __restrict__ nb1, const float* __restrict__ nb2)
{
    __shared__ __align__(16) unsigned short S[4][16][136];
    const int tid = threadIdx.x;
    const int w = tid >> 6, lane = tid & 63;
    const int l15 = lane & 15, quad = lane >> 4;
    const int le = lane >> 2, sub = lane & 3;
    const int t = blockIdx.x * 4 + w;
    if (t >= NN / 16) return;                      // 3125 waves exactly

    {   // gather (fully coalesced): [hb | tmsgb] -> S[16][128]
        unsigned short* Srow = &S[w][le][0];
        const int n = t * 16 + le;
        const unsigned short* hr = hb + (size_t)n * HH + sub * 16;
        *(uint4*)&Srow[sub * 16]     = *(const uint4*)(hr);
        *(uint4*)&Srow[sub * 16 + 8] = *(const uint4*)(hr + 8);
        const unsigned short* tm = tmsgb + (size_t)n * HH + sub * 16;
        *(uint4*)&Srow[64 + sub * 16]     = *(const uint4*)(tm);
        *(uint4*)&Srow[64 + sub * 16 + 8] = *(const uint4*)(tm + 8);
    }
    WFENCE();

    // GEMM1: [16x128] @ nW1[128x64] -> SiLU -> alias cols 0..63
    bf16x8 af[4];
    #pragma unroll
    for (int s = 0; s < 4; ++s)
        af[s] = *(const bf16x8*)&S[w][l15][s * 32 + quad * 8];
    WFENCE();
    float nb1v[4], nb2v[4];
    #pragma unroll
    for (int nt = 0; nt < 4; ++nt) {
        nb1v[nt] = nb1[nt * 16 + l15];
        nb2v[nt] = nb2[nt * 16 + l15];
    }
    #pragma unroll
    for (int nt = 0; nt < 4; ++nt) {
        f32x4 a = {0.f, 0.f, 0.f, 0.f};
        #pragma unroll
        for (int s = 0; s < 4; ++s) {
            bf16x8 bf = *(const bf16x8*)(nw1b + ((s * 4 + nt) * 64 + lane) * 8);
            a = __builtin_amdgcn_mfma_f32_16x16x32_bf16(af[s], bf, a, 0, 0, 0);
        }
        #pragma unroll
        for (int rr = 0; rr < 4; ++rr)
            S[w][quad * 4 + rr][nt * 16 + l15] = bfb(silu_f(a[rr] + nb1v[nt]));
    }
    WFENCE();

    // GEMM2: [16x64] @ nW2[64x64] -> h (no act)
    bf16x8 a2[2];
    #pragma unroll
    for (int s = 0; s < 2; ++s)
        a2[s] = *(const bf16x8*)&S[w][l15][s * 32 + quad * 8];
    #pragma unroll
    for (int nt = 0; nt < 4; ++nt) {
        f32x4 m = {0.f, 0.f, 0.f, 0.f};
        #pragma unroll
        for (int s = 0; s < 2; ++s) {
            bf16x8 bf = *(const bf16x8*)(nw2b + ((s * 4 + nt) * 64 + lane) * 8);
            m = __builtin_amdgcn_mfma_f32_16x16x32_bf16(a2[s], bf, m, 0, 0, 0);
        }
        #pragma unroll
        for (int rr = 0; rr < 4; ++rr) {
            const float v = m[rr] + nb2v[nt];
            const size_t nd = (size_t)(t * 16 + quad * 4 + rr) * HH + nt * 16 + l15;
            h[nd] = v;
            hb[nd] = bfb(v);
        }
    }
}

extern "C" void kernel_launch(void* const* d_in, const int* in_sizes, int n_in,
                              void* d_out, int out_size, void* d_ws, size_t ws_size,
                              hipStream_t stream) {
    const float* x_in  = (const float*)d_in[0];
    const float* h_in  = (const float*)d_in[1];
    const int*   row   = (const int*)d_in[2];
    const int*   col   = (const int*)d_in[3];
    const float* efea  = (const float*)d_in[4];
    const float* emb_W = (const float*)d_in[5];
    const float* emb_b = (const float*)d_in[6];
    const float* eW1   = (const float*)d_in[7];
    const float* eb1   = (const float*)d_in[8];
    const float* eW2   = (const float*)d_in[9];
    const float* eb2   = (const float*)d_in[10];
    const float* cW1   = (const float*)d_in[11];
    const float* cb1   = (const float*)d_in[12];
    const float* cW2   = (const float*)d_in[13];
    const float* cb2   = (const float*)d_in[14];
    const float* nW1   = (const float*)d_in[15];
    const float* nb1   = (const float*)d_in[16];
    const float* nW2   = (const float*)d_in[17];
    const float* nb2   = (const float*)d_in[18];

    float* out = (float*)d_out;
    float* xo = out;                 // N*3 (final x)
    float* ho = out + NN * 3;        // N*64 (final h)

    // workspace layout (16B-aligned segments)
    char* wsb = (char*)d_ws;
    unsigned short* tmsgb = (unsigned short*)(wsb);              //  6,400,000 B
    unsigned short* efs   = (unsigned short*)(wsb + 6400000);    // 12,800,000 B
    unsigned short* hb    = (unsigned short*)(wsb + 19200000);   //  6,400,000 B
    unsigned short* wsW   = (unsigned short*)(wsb + 25600000);   //    122,880 B
    float* x1   = (float*)(wsb + 25722880);                      //    600,000 B
    int* deg    = (int*)(wsb + 26322880);                        //    200,000 B
    int* rowptr = (int*)(wsb + 26522880);                        //    200,004 B
    int* cur    = (int*)(wsb + 26722884);                        //    200,000 B
    int* perm   = (int*)(wsb + 26922884);                        //  3,200,000 B
    int* cs     = (int*)(wsb + 30122884);                        //  3,200,000 B

    // CSR build + sorted-edge materialization (row/col/efea are fixed inputs)
    hipMemsetAsync(deg, 0, NN * sizeof(int), stream);
    hist_kernel<<<MM / 256, 256, 0, stream>>>(row, deg);
    scan_kernel<<<1, 1024, 0, stream>>>(deg, rowptr, cur);
    fillA_kernel<<<MM / 256, 256, 0, stream>>>(row, cur, perm);
    fillB_kernel<<<MM / 256, 256, 0, stream>>>(perm, col, efea, cs, efs);

    prep_kernel<<<240, 256, 0, stream>>>(eW1, eW2, cW1, nW1, nW2, wsW);
    embed_kernel<<<(NN * HH) / 256, 256, 0, stream>>>(h_in, emb_W, emb_b, ho, hb);

    for (int i = 0; i < 2; ++i) {
        const unsigned short* L = wsW + i * 30720;
        const float* xc = (i == 0) ? x_in : x1;
        float*       xn = (i == 0) ? x1   : xo;
        edge_mfma_kernel<<<NN / 4, 256, 0, stream>>>(
            xc, xn, hb, cs, efs, rowptr,
            L, L + 10240, L + 14336,
            eb1 + i * 64, eb2 + i * 64, cb1 + i * 64, cW2 + i * 64, cb2 + i,
            tmsgb);
        node_mfma_kernel<<<(NN / 16 + 3) / 4, 256, 0, stream>>>(
            ho, hb, tmsgb,
            L + 18432, L + 26624, nb1 + i * 64, nb2 + i * 64);
    }
}

// Round 10
// 718.221 us; speedup vs baseline: 1.6283x; 1.6283x over previous
//
#include <hip/hip_runtime.h>
#include <math.h>

#define NN 50000
#define MM 800000
#define HH 64
#define NB_EDGE 1792
#define NTILE 12500                 // MM / 64 edges per block-tile

typedef short bf16x8 __attribute__((ext_vector_type(8)));
typedef float f32x4  __attribute__((ext_vector_type(4)));

// per-wave LDS fence: all LDS regions are wave-private; lockstep + lgkmcnt
// drain replaces __syncthreads
#define WFENCE() asm volatile("s_waitcnt lgkmcnt(0)" ::: "memory")

__device__ __forceinline__ float silu_f(float v) {
    return v * __builtin_amdgcn_rcpf(1.0f + __expf(-v));
}
// round-half-up fp32 -> bf16 bits (0.5 ulp max)
__device__ __forceinline__ unsigned short bfb(float a) {
    return (unsigned short)((__float_as_uint(a) + 0x8000u) >> 16);
}
// pack two f32 -> bf16x2 via v_perm
__device__ __forceinline__ unsigned pk2(float a, float b) {
    return __builtin_amdgcn_perm(__float_as_uint(b) + 0x8000u,
                                 __float_as_uint(a) + 0x8000u, 0x07060302u);
}
__device__ __forceinline__ float b2f(unsigned short s) {
    return __uint_as_float((unsigned)s << 16);
}

// ---------------- CSR build ----------------
__global__ __launch_bounds__(256) void hist_kernel(const int* __restrict__ row,
                                                   int* __restrict__ deg) {
    const int e = blockIdx.x * 256 + threadIdx.x;
    atomicAdd(&deg[row[e]], 1);
}

__global__ __launch_bounds__(1024) void scan_kernel(const int* __restrict__ deg,
                                                    int* __restrict__ rowptr,
                                                    int* __restrict__ cur) {
    __shared__ int ps[1024];
    const int t = threadIdx.x;
    const int C = (NN + 1023) / 1024;              // 49
    const int lo = t * C, hi = (lo + C < NN) ? lo + C : NN;
    int s = 0;
    for (int i = lo; i < hi; ++i) s += deg[i];
    ps[t] = s;
    __syncthreads();
    for (int off = 1; off < 1024; off <<= 1) {
        const int v = (t >= off) ? ps[t - off] : 0;
        __syncthreads();
        ps[t] += v;
        __syncthreads();
    }
    int run = ps[t] - s;                            // exclusive prefix
    for (int i = lo; i < hi; ++i) {
        rowptr[i] = run; cur[i] = run; run += deg[i];
    }
    if (t == 1023) rowptr[NN] = MM;
}

// one-pass counting-sort fill: materialize row/col/edge_fea in sorted order
__global__ __launch_bounds__(256) void fill_kernel(
    const int* __restrict__ row, const int* __restrict__ col,
    const float* __restrict__ efea, int* __restrict__ cur,
    int* __restrict__ rs, int* __restrict__ cs, unsigned short* __restrict__ efs)
{
    const int e = blockIdx.x * 256 + threadIdx.x;
    const int r = row[e];
    const int pos = atomicAdd(&cur[r], 1);
    rs[pos] = r;
    cs[pos] = col[e];
    const float4* ef = (const float4*)(efea + (size_t)e * 8);
    const float4 e0 = ef[0], e1 = ef[1];
    uint4 ue = { pk2(e0.x, e0.y), pk2(e0.z, e0.w), pk2(e1.x, e1.y), pk2(e1.z, e1.w) };
    *(uint4*)(efs + (size_t)pos * 8) = ue;
}

// ---------------- fused: weight pre-swizzle (blocks 0..239) + embedding ----
// per layer (30720 shorts): eW1b@0 (10240), eW2b@10240, cW1b@14336,
// nW1b@18432 (8192), nW2b@26624
__global__ __launch_bounds__(256) void prep_embed_kernel(
    const float* __restrict__ eW1, const float* __restrict__ eW2,
    const float* __restrict__ cW1, const float* __restrict__ nW1,
    const float* __restrict__ nW2, unsigned short* __restrict__ wsW,
    const float* __restrict__ h_in, const float* __restrict__ emb_W,
    const float* __restrict__ emb_b, float* __restrict__ h_out,
    unsigned short* __restrict__ hb)
{
    if (blockIdx.x < 240) {
        const int i = blockIdx.x * 256 + threadIdx.x;     // 0 .. 61439
        const int layer = i / 30720;
        const int rem = i - layer * 30720;
        float val;
        if (rem < 10240) {
            const int j = rem & 7, lane = (rem >> 3) & 63, nt = (rem >> 9) & 3, s = rem >> 11;
            const int kp = s * 32 + ((lane >> 4) << 3) + j;
            const int n  = nt * 16 + (lane & 15);
            if (kp > 136) val = 0.0f;
            else {
                const int k = (kp == 136) ? 0 : kp + 1;   // k'=136 is the r2 row (orig k=0)
                val = eW1[layer * 137 * 64 + k * 64 + n];
            }
        } else if (rem < 14336) {
            const int r2 = rem - 10240;
            const int j = r2 & 7, lane = (r2 >> 3) & 63, nt = (r2 >> 9) & 3, s = r2 >> 11;
            val = eW2[layer * 4096 + (s * 32 + ((lane >> 4) << 3) + j) * 64 + nt * 16 + (lane & 15)];
        } else if (rem < 18432) {
            const int r3 = rem - 14336;
            const int j = r3 & 7, lane = (r3 >> 3) & 63, nt = (r3 >> 9) & 3, s = r3 >> 11;
            val = cW1[layer * 4096 + (s * 32 + ((lane >> 4) << 3) + j) * 64 + nt * 16 + (lane & 15)];
        } else if (rem < 26624) {
            const int r4 = rem - 18432;
            const int j = r4 & 7, lane = (r4 >> 3) & 63, nt = (r4 >> 9) & 3, s = r4 >> 11;
            const int kp = s * 32 + ((lane >> 4) << 3) + j;      // < 128
            val = nW1[layer * 8192 + kp * 64 + nt * 16 + (lane & 15)];
        } else {
            const int r5 = rem - 26624;
            const int j = r5 & 7, lane = (r5 >> 3) & 63, nt = (r5 >> 9) & 3, s = r5 >> 11;
            val = nW2[layer * 4096 + (s * 32 + ((lane >> 4) << 3) + j) * 64 + nt * 16 + (lane & 15)];
        }
        wsW[i] = bfb(val);
    } else {
        const int idx = (blockIdx.x - 240) * 256 + threadIdx.x;   // over N*64
        const int n = idx >> 6, j = idx & 63;
        float acc = emb_b[j];
        #pragma unroll
        for (int k = 0; k < 16; ++k)
            acc += h_in[n * 16 + k] * emb_W[k * HH + j];
        h_out[idx] = acc;
        hb[idx] = bfb(acc);
    }
}

// ---------------- MFMA edge kernel: 16 sorted edges per wave ----------------
// Segmented atomic flush to tmsg/sum_f (rows sorted -> ~2 atomics/col/tile).
// LDS 23040 B/block -> 7 blocks/CU; launch_bounds(256,7).
__global__ __launch_bounds__(256, 7) void edge_mfma_kernel(
    const float* __restrict__ x, const unsigned short* __restrict__ hb,
    const int* __restrict__ rs, const int* __restrict__ cs,
    const unsigned short* __restrict__ efs,
    const unsigned short* __restrict__ w1b, const unsigned short* __restrict__ w2b,
    const unsigned short* __restrict__ cw1b,
    const float* __restrict__ b1, const float* __restrict__ b2,
    const float* __restrict__ cb1, const float* __restrict__ cw2,
    const float* __restrict__ cb2,
    float* __restrict__ sum_f, float* __restrict__ tmsg)
{
    __shared__ __align__(16) unsigned short S[4][16][168];
    __shared__ float RV[4][16][4];
    __shared__ int   RI[4][16];

    const int tid = threadIdx.x;
    const int w = tid >> 6, lane = tid & 63;
    const int l15 = lane & 15, quad = lane >> 4;
    const int le = lane >> 2, sub = lane & 3;

    float b1v[4], b2v[4], cb1v[4], cw2v[4];
    #pragma unroll
    for (int nt = 0; nt < 4; ++nt) {
        b1v[nt]  = b1[nt * 16 + l15];
        b2v[nt]  = b2[nt * 16 + l15];
        cb1v[nt] = cb1[nt * 16 + l15];
        cw2v[nt] = cw2[nt * 16 + l15];
    }
    const float cb2s = cb2[0];

    {   // zero the K-pad [138,160) once; never overwritten afterwards
        unsigned short* Sr = &S[w][le][0];
        if (sub == 0) {
            *(unsigned*)&Sr[138] = 0u; *(unsigned*)&Sr[140] = 0u; *(unsigned*)&Sr[142] = 0u;
        } else if (sub == 1) {
            *(unsigned*)&Sr[144] = 0u; *(unsigned*)&Sr[146] = 0u;
            *(unsigned*)&Sr[148] = 0u; *(unsigned*)&Sr[150] = 0u;
        } else if (sub == 2) {
            *(unsigned*)&Sr[152] = 0u; *(unsigned*)&Sr[154] = 0u;
            *(unsigned*)&Sr[156] = 0u; *(unsigned*)&Sr[158] = 0u;
        }
    }
    WFENCE();

    for (int bt = blockIdx.x; bt < NTILE; bt += NB_EDGE) {
        const int t = bt * 4 + w;
        const int p = t * 16 + le;           // sorted edge position
        const int r = rs[p], c = cs[p];

        // ---- gather: 4 lanes per edge, bf16 uint4 copies ----
        unsigned short* Srow = &S[w][le][0];
        {
            const unsigned short* hr = hb + (size_t)r * HH + sub * 16;
            uint4 u0 = *(const uint4*)(hr);
            uint4 u1 = *(const uint4*)(hr + 8);
            *(uint4*)&Srow[sub * 16]     = u0;
            *(uint4*)&Srow[sub * 16 + 8] = u1;
            const unsigned short* hc = hb + (size_t)c * HH + sub * 16;
            uint4 v0 = *(const uint4*)(hc);
            uint4 v1 = *(const uint4*)(hc + 8);
            *(uint4*)&Srow[64 + sub * 16]     = v0;
            *(uint4*)&Srow[64 + sub * 16 + 8] = v1;
        }
        if (sub == 0) {
            const float rx = x[3 * r + 0] - x[3 * c + 0];
            const float ry = x[3 * r + 1] - x[3 * c + 1];
            const float rz = x[3 * r + 2] - x[3 * c + 2];
            const float r2 = rx * rx + ry * ry + rz * rz;
            RV[w][le][0] = rx; RV[w][le][1] = ry; RV[w][le][2] = rz;
            RI[w][le] = r;
            *(unsigned*)&Srow[136] = (unsigned)bfb(r2);   // zeroes col 137 too
        } else if (sub == 1) {
            *(uint4*)&Srow[128] = *(const uint4*)(efs + (size_t)p * 8);
        }
        WFENCE();

        // ---- GEMM1: S[16x160] @ W1[160x64] -> H1 (alias cols 0..63) ----
        bf16x8 af[5];
        #pragma unroll
        for (int s = 0; s < 5; ++s)
            af[s] = *(const bf16x8*)&S[w][l15][s * 32 + quad * 8];
        WFENCE();   // af in regs before H1 overwrites the same cols
        #pragma unroll
        for (int nt = 0; nt < 4; ++nt) {
            f32x4 a = {0.f, 0.f, 0.f, 0.f};
            #pragma unroll
            for (int s = 0; s < 5; ++s) {
                bf16x8 bf = *(const bf16x8*)(w1b + ((s * 4 + nt) * 64 + lane) * 8);
                a = __builtin_amdgcn_mfma_f32_16x16x32_bf16(af[s], bf, a, 0, 0, 0);
            }
            #pragma unroll
            for (int rr = 0; rr < 4; ++rr)
                S[w][quad * 4 + rr][nt * 16 + l15] = bfb(silu_f(a[rr] + b1v[nt]));
        }
        WFENCE();

        // ---- GEMM2: H1 @ W2 -> msg (alias back into cols 0..63) ----
        bf16x8 a2[2];
        #pragma unroll
        for (int s = 0; s < 2; ++s)
            a2[s] = *(const bf16x8*)&S[w][l15][s * 32 + quad * 8];
        WFENCE();   // a2 in regs before MS overwrites
        #pragma unroll
        for (int nt = 0; nt < 4; ++nt) {
            f32x4 m = {0.f, 0.f, 0.f, 0.f};
            #pragma unroll
            for (int s = 0; s < 2; ++s) {
                bf16x8 bf = *(const bf16x8*)(w2b + ((s * 4 + nt) * 64 + lane) * 8);
                m = __builtin_amdgcn_mfma_f32_16x16x32_bf16(a2[s], bf, m, 0, 0, 0);
            }
            #pragma unroll
            for (int rr = 0; rr < 4; ++rr)
                S[w][quad * 4 + rr][nt * 16 + l15] = bfb(silu_f(m[rr] + b2v[nt]));
        }
        WFENCE();

        // ---- GEMM3: msg @ cW1 -> c1; dot cW2 -> cm (cols 160..162) ----
        bf16x8 a3[2];
        #pragma unroll
        for (int s = 0; s < 2; ++s)
            a3[s] = *(const bf16x8*)&S[w][l15][s * 32 + quad * 8];
        float pr[4] = {0.f, 0.f, 0.f, 0.f};
        #pragma unroll
        for (int nt = 0; nt < 4; ++nt) {
            f32x4 q = {0.f, 0.f, 0.f, 0.f};
            #pragma unroll
            for (int s = 0; s < 2; ++s) {
                bf16x8 bf = *(const bf16x8*)(cw1b + ((s * 4 + nt) * 64 + lane) * 8);
                q = __builtin_amdgcn_mfma_f32_16x16x32_bf16(a3[s], bf, q, 0, 0, 0);
            }
            #pragma unroll
            for (int rr = 0; rr < 4; ++rr)
                pr[rr] += silu_f(q[rr] + cb1v[nt]) * cw2v[nt];
        }
        #pragma unroll
        for (int rr = 0; rr < 4; ++rr) {
            float tt = pr[rr];
            tt += __shfl_xor(tt, 1, 64);
            tt += __shfl_xor(tt, 2, 64);
            tt += __shfl_xor(tt, 4, 64);
            tt += __shfl_xor(tt, 8, 64);
            if (l15 == 0) *(float*)&S[w][quad * 4 + rr][160] = tt + cb2s;
        }
        WFENCE();

        // ---- segmented flush: rows sorted by RI within the tile ----
        {   // msg -> tmsg, one lane per column (~2 atomics/col on avg)
            float acc = b2f(S[w][0][lane]);
            int cur_r = RI[w][0];
            #pragma unroll
            for (int g = 1; g < 16; ++g) {
                const int ri = RI[w][g];
                const float v = b2f(S[w][g][lane]);
                if (ri != cur_r) {
                    atomicAdd(&tmsg[(size_t)cur_r * HH + lane], acc);
                    acc = 0.f; cur_r = ri;
                }
                acc += v;
            }
            atomicAdd(&tmsg[(size_t)cur_r * HH + lane], acc);
        }
        if (lane < 3) {   // f = rij*cm -> sum_f
            float acc = RV[w][0][lane] * (*(const float*)&S[w][0][160]);
            int cur_r = RI[w][0];
            #pragma unroll
            for (int g = 1; g < 16; ++g) {
                const int ri = RI[w][g];
                const float v = RV[w][g][lane] * (*(const float*)&S[w][g][160]);
                if (ri != cur_r) {
                    atomicAdd(&sum_f[3 * cur_r + lane], acc);
                    acc = 0.f; cur_r = ri;
                }
                acc += v;
            }
            atomicAdd(&sum_f[3 * cur_r + lane], acc);
        }
        WFENCE();
    }
}

// ---------------- MFMA node kernel: 16 nodes per wave ----------------
__global__ __launch_bounds__(256) void node_mfma_kernel(
    float* __restrict__ x, float* __restrict__ h,
    unsigned short* __restrict__ hb,
    const float* __restrict__ sum_f, const int* __restrict__ rowptr,
    const float* __restrict__ tmsg,
    const unsigned short* __restrict__ nw1b, const unsigned short* __restrict__ nw2b,
    const float* __restrict__ nb1, const float* __restrict__ nb2)
{
    __shared__ __align__(16) unsigned short S[4][16][136];
    const int tid = threadIdx.x;
    const int w = tid >> 6, lane = tid & 63;
    const int l15 = lane & 15, quad = lane >> 4;
    const int le = lane >> 2, sub = lane & 3;
    const int t = blockIdx.x * 4 + w;
    if (t >= NN / 16) return;                      // 3125 waves exactly

    // gather (fully coalesced): [hb | bf16(tmsg)] -> S[16][128]
    {
        unsigned short* Srow = &S[w][le][0];
        const int n = t * 16 + le;
        const unsigned short* hr = hb + (size_t)n * HH + sub * 16;
        *(uint4*)&Srow[sub * 16]     = *(const uint4*)(hr);
        *(uint4*)&Srow[sub * 16 + 8] = *(const uint4*)(hr + 8);
        const float4* tm = (const float4*)(tmsg + (size_t)n * HH + sub * 16);
        float4 t0 = tm[0], t1 = tm[1], t2 = tm[2], t3 = tm[3];
        uint4 u0 = { pk2(t0.x, t0.y), pk2(t0.z, t0.w), pk2(t1.x, t1.y), pk2(t1.z, t1.w) };
        uint4 u1 = { pk2(t2.x, t2.y), pk2(t2.z, t2.w), pk2(t3.x, t3.y), pk2(t3.z, t3.w) };
        *(uint4*)&Srow[64 + sub * 16]     = u0;
        *(uint4*)&Srow[64 + sub * 16 + 8] = u1;
    }
    // x update: one lane per node
    if (lane < 16) {
        const int nn = t * 16 + lane;
        const float cn = fmaxf((float)(rowptr[nn + 1] - rowptr[nn]), 1.0f);
        const float rc = __builtin_amdgcn_rcpf(cn);
        #pragma unroll
        for (int d3 = 0; d3 < 3; ++d3) {
            float tf = sum_f[3 * nn + d3] * rc;
            tf = fminf(fmaxf(tf, -100.0f), 100.0f);
            x[3 * nn + d3] += tf;
        }
    }
    WFENCE();

    // GEMM1: [16x128] @ nW1[128x64] -> SiLU -> alias cols 0..63
    bf16x8 af[4];
    #pragma unroll
    for (int s = 0; s < 4; ++s)
        af[s] = *(const bf16x8*)&S[w][l15][s * 32 + quad * 8];
    WFENCE();
    float nb1v[4], nb2v[4];
    #pragma unroll
    for (int nt = 0; nt < 4; ++nt) {
        nb1v[nt] = nb1[nt * 16 + l15];
        nb2v[nt] = nb2[nt * 16 + l15];
    }
    #pragma unroll
    for (int nt = 0; nt < 4; ++nt) {
        f32x4 a = {0.f, 0.f, 0.f, 0.f};
        #pragma unroll
        for (int s = 0; s < 4; ++s) {
            bf16x8 bf = *(const bf16x8*)(nw1b + ((s * 4 + nt) * 64 + lane) * 8);
            a = __builtin_amdgcn_mfma_f32_16x16x32_bf16(af[s], bf, a, 0, 0, 0);
        }
        #pragma unroll
        for (int rr = 0; rr < 4; ++rr)
            S[w][quad * 4 + rr][nt * 16 + l15] = bfb(silu_f(a[rr] + nb1v[nt]));
    }
    WFENCE();

    // GEMM2: [16x64] @ nW2[64x64] -> h (no act)
    bf16x8 a2[2];
    #pragma unroll
    for (int s = 0; s < 2; ++s)
        a2[s] = *(const bf16x8*)&S[w][l15][s * 32 + quad * 8];
    #pragma unroll
    for (int nt = 0; nt < 4; ++nt) {
        f32x4 m = {0.f, 0.f, 0.f, 0.f};
        #pragma unroll
        for (int s = 0; s < 2; ++s) {
            bf16x8 bf = *(const bf16x8*)(nw2b + ((s * 4 + nt) * 64 + lane) * 8);
            m = __builtin_amdgcn_mfma_f32_16x16x32_bf16(a2[s], bf, m, 0, 0, 0);
        }
        #pragma unroll
        for (int rr = 0; rr < 4; ++rr) {
            const float v = m[rr] + nb2v[nt];
            const size_t nd = (size_t)(t * 16 + quad * 4 + rr) * HH + nt * 16 + l15;
            h[nd] = v;
            hb[nd] = bfb(v);
        }
    }
}

extern "C" void kernel_launch(void* const* d_in, const int* in_sizes, int n_in,
                              void* d_out, int out_size, void* d_ws, size_t ws_size,
                              hipStream_t stream) {
    const float* x_in  = (const float*)d_in[0];
    const float* h_in  = (const float*)d_in[1];
    const int*   row   = (const int*)d_in[2];
    const int*   col   = (const int*)d_in[3];
    const float* efea  = (const float*)d_in[4];
    const float* emb_W = (const float*)d_in[5];
    const float* emb_b = (const float*)d_in[6];
    const float* eW1   = (const float*)d_in[7];
    const float* eb1   = (const float*)d_in[8];
    const float* eW2   = (const float*)d_in[9];
    const float* eb2   = (const float*)d_in[10];
    const float* cW1   = (const float*)d_in[11];
    const float* cb1   = (const float*)d_in[12];
    const float* cW2   = (const float*)d_in[13];
    const float* cb2   = (const float*)d_in[14];
    const float* nW1   = (const float*)d_in[15];
    const float* nb1   = (const float*)d_in[16];
    const float* nW2   = (const float*)d_in[17];
    const float* nb2   = (const float*)d_in[18];

    float* out = (float*)d_out;
    float* xo = out;                 // N*3
    float* ho = out + NN * 3;        // N*64

    // workspace layout (16B-aligned segments first)
    char* wsb = (char*)d_ws;
    float* sum_f = (float*)wsb;                               //    600,000 B
    float* tmsg  = (float*)(wsb + 600000);                    // 12,800,000 B
    unsigned short* efs = (unsigned short*)(wsb + 13400000);  // 12,800,000 B
    unsigned short* hb  = (unsigned short*)(wsb + 26200000);  //  6,400,000 B
    unsigned short* wsW = (unsigned short*)(wsb + 32600000);  //    122,880 B
    int* deg    = (int*)(wsb + 32722880);                     //    200,000 B
    int* rowptr = (int*)(wsb + 32922880);                     //    200,004 B
    int* cur    = (int*)(wsb + 33122884);                     //    200,000 B
    int* rs     = (int*)(wsb + 33322884);                     //  3,200,000 B
    int* cs     = (int*)(wsb + 36522884);                     //  3,200,000 B

    // CSR build + sorted-edge materialization (row/col/efea are fixed inputs)
    hipMemsetAsync(deg, 0, NN * sizeof(int), stream);
    hist_kernel<<<MM / 256, 256, 0, stream>>>(row, deg);
    scan_kernel<<<1, 1024, 0, stream>>>(deg, rowptr, cur);
    fill_kernel<<<MM / 256, 256, 0, stream>>>(row, col, efea, cur, rs, cs, efs);

    hipMemcpyAsync(xo, x_in, (size_t)NN * 3 * sizeof(float),
                   hipMemcpyDeviceToDevice, stream);
    prep_embed_kernel<<<240 + (NN * HH) / 256, 256, 0, stream>>>(
        eW1, eW2, cW1, nW1, nW2, wsW, h_in, emb_W, emb_b, ho, hb);

    for (int i = 0; i < 2; ++i) {
        hipMemsetAsync(wsb, 0, 13400000, stream);   // sum_f + tmsg
        const unsigned short* L = wsW + i * 30720;
        edge_mfma_kernel<<<NB_EDGE, 256, 0, stream>>>(
            xo, hb, rs, cs, efs,
            L, L + 10240, L + 14336,
            eb1 + i * 64, eb2 + i * 64, cb1 + i * 64, cW2 + i * 64, cb2 + i,
            sum_f, tmsg);
        node_mfma_kernel<<<(NN / 16 + 3) / 4, 256, 0, stream>>>(
            xo, ho, hb, sum_f, rowptr, tmsg,
            L + 18432, L + 26624, nb1 + i * 64, nb2 + i * 64);
    }
}

// Round 11
// 608.494 us; speedup vs baseline: 1.9219x; 1.1803x over previous
//
#include <hip/hip_runtime.h>
#include <math.h>

#define NN 50000
#define MM 800000
#define HH 64
#define NB_EDGE 1792
#define NTILE 12500                 // MM / 64 edges per block-tile
#define RPX 1563                    // ceil(NTILE/8) tiles per XCD range

typedef short bf16x8 __attribute__((ext_vector_type(8)));
typedef float f32x4  __attribute__((ext_vector_type(4)));

// per-wave LDS fence: all LDS regions are wave-private; lockstep + lgkmcnt
// drain replaces __syncthreads
#define WFENCE() asm volatile("s_waitcnt lgkmcnt(0)" ::: "memory")

__device__ __forceinline__ float silu_f(float v) {
    return v * __builtin_amdgcn_rcpf(1.0f + __expf(-v));
}
// round-half-up fp32 -> bf16 bits (0.5 ulp max)
__device__ __forceinline__ unsigned short bfb(float a) {
    return (unsigned short)((__float_as_uint(a) + 0x8000u) >> 16);
}
// pack two f32 -> bf16x2 via v_perm
__device__ __forceinline__ unsigned pk2(float a, float b) {
    return __builtin_amdgcn_perm(__float_as_uint(b) + 0x8000u,
                                 __float_as_uint(a) + 0x8000u, 0x07060302u);
}
__device__ __forceinline__ float b2f(unsigned short s) {
    return __uint_as_float((unsigned)s << 16);
}

// ---------------- CSR build ----------------
__global__ __launch_bounds__(256) void hist_kernel(const int* __restrict__ row,
                                                   int* __restrict__ deg) {
    const int e = blockIdx.x * 256 + threadIdx.x;
    atomicAdd(&deg[row[e]], 1);
}

// parallel scan, phase A: 200 blocks x 250-node chunks -> blocksum
__global__ __launch_bounds__(256) void scanA_kernel(const int* __restrict__ deg,
                                                    int* __restrict__ bsum) {
    __shared__ int ps[256];
    const int t = threadIdx.x;
    const int base = blockIdx.x * 250;
    int v = (t < 250) ? deg[base + t] : 0;
    ps[t] = v;
    __syncthreads();
    for (int off = 1; off < 256; off <<= 1) {
        const int u = (t >= off) ? ps[t - off] : 0;
        __syncthreads();
        ps[t] += u;
        __syncthreads();
    }
    if (t == 255) bsum[blockIdx.x] = ps[255];
}

// phase B: exclusive scan of 200 blocksums (single small block)
__global__ __launch_bounds__(256) void scanB_kernel(int* __restrict__ bsum,
                                                    int* __restrict__ boff) {
    __shared__ int ps[256];
    const int t = threadIdx.x;
    int v = (t < 200) ? bsum[t] : 0;
    ps[t] = v;
    __syncthreads();
    for (int off = 1; off < 256; off <<= 1) {
        const int u = (t >= off) ? ps[t - off] : 0;
        __syncthreads();
        ps[t] += u;
        __syncthreads();
    }
    if (t < 200) boff[t] = ps[t] - v;     // exclusive
}

// phase C: per-chunk exclusive scan + global offset -> rowptr, cur
__global__ __launch_bounds__(256) void scanC_kernel(const int* __restrict__ deg,
                                                    const int* __restrict__ boff,
                                                    int* __restrict__ rowptr,
                                                    int* __restrict__ cur) {
    __shared__ int ps[256];
    const int t = threadIdx.x;
    const int base = blockIdx.x * 250;
    int v = (t < 250) ? deg[base + t] : 0;
    ps[t] = v;
    __syncthreads();
    for (int off = 1; off < 256; off <<= 1) {
        const int u = (t >= off) ? ps[t - off] : 0;
        __syncthreads();
        ps[t] += u;
        __syncthreads();
    }
    if (t < 250) {
        const int r = boff[blockIdx.x] + ps[t] - v;   // exclusive prefix
        rowptr[base + t] = r;
        cur[base + t] = r;
    }
    if (blockIdx.x == 199 && t == 255) rowptr[NN] = MM;
}

// one-pass counting-sort fill: materialize row/col/edge_fea in sorted order
__global__ __launch_bounds__(256) void fill_kernel(
    const int* __restrict__ row, const int* __restrict__ col,
    const float* __restrict__ efea, int* __restrict__ cur,
    int* __restrict__ rs, int* __restrict__ cs, unsigned short* __restrict__ efs)
{
    const int e = blockIdx.x * 256 + threadIdx.x;
    const int r = row[e];
    const int pos = atomicAdd(&cur[r], 1);
    rs[pos] = r;
    cs[pos] = col[e];
    const float4* ef = (const float4*)(efea + (size_t)e * 8);
    const float4 e0 = ef[0], e1 = ef[1];
    uint4 ue = { pk2(e0.x, e0.y), pk2(e0.z, e0.w), pk2(e1.x, e1.y), pk2(e1.z, e1.w) };
    *(uint4*)(efs + (size_t)pos * 8) = ue;
}

// ---------------- fused: weight pre-swizzle (blocks 0..239) + embedding ----
// per layer (30720 shorts): eW1b@0 (10240), eW2b@10240, cW1b@14336,
// nW1b@18432 (8192), nW2b@26624
__global__ __launch_bounds__(256) void prep_embed_kernel(
    const float* __restrict__ eW1, const float* __restrict__ eW2,
    const float* __restrict__ cW1, const float* __restrict__ nW1,
    const float* __restrict__ nW2, unsigned short* __restrict__ wsW,
    const float* __restrict__ h_in, const float* __restrict__ emb_W,
    const float* __restrict__ emb_b, float* __restrict__ h_out,
    unsigned short* __restrict__ hb)
{
    if (blockIdx.x < 240) {
        const int i = blockIdx.x * 256 + threadIdx.x;     // 0 .. 61439
        const int layer = i / 30720;
        const int rem = i - layer * 30720;
        float val;
        if (rem < 10240) {
            const int j = rem & 7, lane = (rem >> 3) & 63, nt = (rem >> 9) & 3, s = rem >> 11;
            const int kp = s * 32 + ((lane >> 4) << 3) + j;
            const int n  = nt * 16 + (lane & 15);
            if (kp > 136) val = 0.0f;
            else {
                const int k = (kp == 136) ? 0 : kp + 1;   // k'=136 is the r2 row (orig k=0)
                val = eW1[layer * 137 * 64 + k * 64 + n];
            }
        } else if (rem < 14336) {
            const int r2 = rem - 10240;
            const int j = r2 & 7, lane = (r2 >> 3) & 63, nt = (r2 >> 9) & 3, s = r2 >> 11;
            val = eW2[layer * 4096 + (s * 32 + ((lane >> 4) << 3) + j) * 64 + nt * 16 + (lane & 15)];
        } else if (rem < 18432) {
            const int r3 = rem - 14336;
            const int j = r3 & 7, lane = (r3 >> 3) & 63, nt = (r3 >> 9) & 3, s = r3 >> 11;
            val = cW1[layer * 4096 + (s * 32 + ((lane >> 4) << 3) + j) * 64 + nt * 16 + (lane & 15)];
        } else if (rem < 26624) {
            const int r4 = rem - 18432;
            const int j = r4 & 7, lane = (r4 >> 3) & 63, nt = (r4 >> 9) & 3, s = r4 >> 11;
            const int kp = s * 32 + ((lane >> 4) << 3) + j;      // < 128
            val = nW1[layer * 8192 + kp * 64 + nt * 16 + (lane & 15)];
        } else {
            const int r5 = rem - 26624;
            const int j = r5 & 7, lane = (r5 >> 3) & 63, nt = (r5 >> 9) & 3, s = r5 >> 11;
            val = nW2[layer * 4096 + (s * 32 + ((lane >> 4) << 3) + j) * 64 + nt * 16 + (lane & 15)];
        }
        wsW[i] = bfb(val);
    } else {
        const int idx = (blockIdx.x - 240) * 256 + threadIdx.x;   // over N*64
        const int n = idx >> 6, j = idx & 63;
        float acc = emb_b[j];
        #pragma unroll
        for (int k = 0; k < 16; ++k)
            acc += h_in[n * 16 + k] * emb_W[k * HH + j];
        h_out[idx] = acc;
        hb[idx] = bfb(acc);
    }
}

// ---------------- MFMA edge kernel: 16 sorted edges per wave ----------------
// XCD-range swizzle: blocks on XCD k (blockIdx&7 heuristic) process sorted-tile
// range [k*RPX, (k+1)*RPX) -> row-side hb reads + tmsg atomic lines stay in
// that XCD's L2 (1.6 MB < 4 MB). Perf-only: any mapping is correct.
__global__ __launch_bounds__(256, 7) void edge_mfma_kernel(
    const float* __restrict__ x, const unsigned short* __restrict__ hb,
    const int* __restrict__ rs, const int* __restrict__ cs,
    const unsigned short* __restrict__ efs,
    const unsigned short* __restrict__ w1b, const unsigned short* __restrict__ w2b,
    const unsigned short* __restrict__ cw1b,
    const float* __restrict__ b1, const float* __restrict__ b2,
    const float* __restrict__ cb1, const float* __restrict__ cw2,
    const float* __restrict__ cb2,
    float* __restrict__ sum_f, float* __restrict__ tmsg)
{
    __shared__ __align__(16) unsigned short S[4][16][168];
    __shared__ float RV[4][16][4];
    __shared__ int   RI[4][16];

    const int tid = threadIdx.x;
    const int w = tid >> 6, lane = tid & 63;
    const int l15 = lane & 15, quad = lane >> 4;
    const int le = lane >> 2, sub = lane & 3;

    float b1v[4], b2v[4], cb1v[4], cw2v[4];
    #pragma unroll
    for (int nt = 0; nt < 4; ++nt) {
        b1v[nt]  = b1[nt * 16 + l15];
        b2v[nt]  = b2[nt * 16 + l15];
        cb1v[nt] = cb1[nt * 16 + l15];
        cw2v[nt] = cw2[nt * 16 + l15];
    }
    const float cb2s = cb2[0];

    {   // zero the K-pad [138,160) once; never overwritten afterwards
        unsigned short* Sr = &S[w][le][0];
        if (sub == 0) {
            *(unsigned*)&Sr[138] = 0u; *(unsigned*)&Sr[140] = 0u; *(unsigned*)&Sr[142] = 0u;
        } else if (sub == 1) {
            *(unsigned*)&Sr[144] = 0u; *(unsigned*)&Sr[146] = 0u;
            *(unsigned*)&Sr[148] = 0u; *(unsigned*)&Sr[150] = 0u;
        } else if (sub == 2) {
            *(unsigned*)&Sr[152] = 0u; *(unsigned*)&Sr[154] = 0u;
            *(unsigned*)&Sr[156] = 0u; *(unsigned*)&Sr[158] = 0u;
        }
    }
    WFENCE();

    const int xcd  = blockIdx.x & 7;
    const int bsub = blockIdx.x >> 3;              // 0 .. NB_EDGE/8-1
    const int lo   = xcd * RPX;
    int hi = lo + RPX; if (hi > NTILE) hi = NTILE;

    for (int bt = lo + bsub; bt < hi; bt += NB_EDGE / 8) {
        const int t = bt * 4 + w;
        const int p = t * 16 + le;           // sorted edge position
        const int r = rs[p], c = cs[p];

        // ---- gather: 4 lanes per edge, bf16 uint4 copies ----
        unsigned short* Srow = &S[w][le][0];
        {
            const unsigned short* hr = hb + (size_t)r * HH + sub * 16;
            uint4 u0 = *(const uint4*)(hr);
            uint4 u1 = *(const uint4*)(hr + 8);
            *(uint4*)&Srow[sub * 16]     = u0;
            *(uint4*)&Srow[sub * 16 + 8] = u1;
            const unsigned short* hc = hb + (size_t)c * HH + sub * 16;
            uint4 v0 = *(const uint4*)(hc);
            uint4 v1 = *(const uint4*)(hc + 8);
            *(uint4*)&Srow[64 + sub * 16]     = v0;
            *(uint4*)&Srow[64 + sub * 16 + 8] = v1;
        }
        if (sub == 0) {
            const float rx = x[3 * r + 0] - x[3 * c + 0];
            const float ry = x[3 * r + 1] - x[3 * c + 1];
            const float rz = x[3 * r + 2] - x[3 * c + 2];
            const float r2 = rx * rx + ry * ry + rz * rz;
            RV[w][le][0] = rx; RV[w][le][1] = ry; RV[w][le][2] = rz;
            RI[w][le] = r;
            *(unsigned*)&Srow[136] = (unsigned)bfb(r2);   // zeroes col 137 too
        } else if (sub == 1) {
            *(uint4*)&Srow[128] = *(const uint4*)(efs + (size_t)p * 8);
        }
        WFENCE();

        // ---- GEMM1: S[16x160] @ W1[160x64] -> H1 (alias cols 0..63) ----
        bf16x8 af[5];
        #pragma unroll
        for (int s = 0; s < 5; ++s)
            af[s] = *(const bf16x8*)&S[w][l15][s * 32 + quad * 8];
        WFENCE();   // af in regs before H1 overwrites the same cols
        #pragma unroll
        for (int nt = 0; nt < 4; ++nt) {
            f32x4 a = {0.f, 0.f, 0.f, 0.f};
            #pragma unroll
            for (int s = 0; s < 5; ++s) {
                bf16x8 bf = *(const bf16x8*)(w1b + ((s * 4 + nt) * 64 + lane) * 8);
                a = __builtin_amdgcn_mfma_f32_16x16x32_bf16(af[s], bf, a, 0, 0, 0);
            }
            #pragma unroll
            for (int rr = 0; rr < 4; ++rr)
                S[w][quad * 4 + rr][nt * 16 + l15] = bfb(silu_f(a[rr] + b1v[nt]));
        }
        WFENCE();

        // ---- GEMM2: H1 @ W2 -> msg (alias back into cols 0..63) ----
        bf16x8 a2[2];
        #pragma unroll
        for (int s = 0; s < 2; ++s)
            a2[s] = *(const bf16x8*)&S[w][l15][s * 32 + quad * 8];
        WFENCE();   // a2 in regs before MS overwrites
        #pragma unroll
        for (int nt = 0; nt < 4; ++nt) {
            f32x4 m = {0.f, 0.f, 0.f, 0.f};
            #pragma unroll
            for (int s = 0; s < 2; ++s) {
                bf16x8 bf = *(const bf16x8*)(w2b + ((s * 4 + nt) * 64 + lane) * 8);
                m = __builtin_amdgcn_mfma_f32_16x16x32_bf16(a2[s], bf, m, 0, 0, 0);
            }
            #pragma unroll
            for (int rr = 0; rr < 4; ++rr)
                S[w][quad * 4 + rr][nt * 16 + l15] = bfb(silu_f(m[rr] + b2v[nt]));
        }
        WFENCE();

        // ---- GEMM3: msg @ cW1 -> c1; dot cW2 -> cm (cols 160..162) ----
        bf16x8 a3[2];
        #pragma unroll
        for (int s = 0; s < 2; ++s)
            a3[s] = *(const bf16x8*)&S[w][l15][s * 32 + quad * 8];
        float pr[4] = {0.f, 0.f, 0.f, 0.f};
        #pragma unroll
        for (int nt = 0; nt < 4; ++nt) {
            f32x4 q = {0.f, 0.f, 0.f, 0.f};
            #pragma unroll
            for (int s = 0; s < 2; ++s) {
                bf16x8 bf = *(const bf16x8*)(cw1b + ((s * 4 + nt) * 64 + lane) * 8);
                q = __builtin_amdgcn_mfma_f32_16x16x32_bf16(a3[s], bf, q, 0, 0, 0);
            }
            #pragma unroll
            for (int rr = 0; rr < 4; ++rr)
                pr[rr] += silu_f(q[rr] + cb1v[nt]) * cw2v[nt];
        }
        #pragma unroll
        for (int rr = 0; rr < 4; ++rr) {
            float tt = pr[rr];
            tt += __shfl_xor(tt, 1, 64);
            tt += __shfl_xor(tt, 2, 64);
            tt += __shfl_xor(tt, 4, 64);
            tt += __shfl_xor(tt, 8, 64);
            if (l15 == 0) *(float*)&S[w][quad * 4 + rr][160] = tt + cb2s;
        }
        WFENCE();

        // ---- segmented flush: rows sorted by RI within the tile ----
        {   // msg -> tmsg, one lane per column (~2 atomics/col on avg)
            float acc = b2f(S[w][0][lane]);
            int cur_r = RI[w][0];
            #pragma unroll
            for (int g = 1; g < 16; ++g) {
                const int ri = RI[w][g];
                const float v = b2f(S[w][g][lane]);
                if (ri != cur_r) {
                    atomicAdd(&tmsg[(size_t)cur_r * HH + lane], acc);
                    acc = 0.f; cur_r = ri;
                }
                acc += v;
            }
            atomicAdd(&tmsg[(size_t)cur_r * HH + lane], acc);
        }
        if (lane < 3) {   // f = rij*cm -> sum_f
            float acc = RV[w][0][lane] * (*(const float*)&S[w][0][160]);
            int cur_r = RI[w][0];
            #pragma unroll
            for (int g = 1; g < 16; ++g) {
                const int ri = RI[w][g];
                const float v = RV[w][g][lane] * (*(const float*)&S[w][g][160]);
                if (ri != cur_r) {
                    atomicAdd(&sum_f[3 * cur_r + lane], acc);
                    acc = 0.f; cur_r = ri;
                }
                acc += v;
            }
            atomicAdd(&sum_f[3 * cur_r + lane], acc);
        }
        WFENCE();
    }
}

// ---------------- MFMA node kernel: 16 nodes per wave ----------------
__global__ __launch_bounds__(256) void node_mfma_kernel(
    float* __restrict__ x, float* __restrict__ h,
    unsigned short* __restrict__ hb,
    const float* __restrict__ sum_f, const int* __restrict__ rowptr,
    const float* __restrict__ tmsg,
    const unsigned short* __restrict__ nw1b, const unsigned short* __restrict__ nw2b,
    const float* __restrict__ nb1, const float* __restrict__ nb2)
{
    __shared__ __align__(16) unsigned short S[4][16][136];
    const int tid = threadIdx.x;
    const int w = tid >> 6, lane = tid & 63;
    const int l15 = lane & 15, quad = lane >> 4;
    const int le = lane >> 2, sub = lane & 3;
    const int t = blockIdx.x * 4 + w;
    if (t >= NN / 16) return;                      // 3125 waves exactly

    // gather (fully coalesced): [hb | bf16(tmsg)] -> S[16][128]
    {
        unsigned short* Srow = &S[w][le][0];
        const int n = t * 16 + le;
        const unsigned short* hr = hb + (size_t)n * HH + sub * 16;
        *(uint4*)&Srow[sub * 16]     = *(const uint4*)(hr);
        *(uint4*)&Srow[sub * 16 + 8] = *(const uint4*)(hr + 8);
        const float4* tm = (const float4*)(tmsg + (size_t)n * HH + sub * 16);
        float4 t0 = tm[0], t1 = tm[1], t2 = tm[2], t3 = tm[3];
        uint4 u0 = { pk2(t0.x, t0.y), pk2(t0.z, t0.w), pk2(t1.x, t1.y), pk2(t1.z, t1.w) };
        uint4 u1 = { pk2(t2.x, t2.y), pk2(t2.z, t2.w), pk2(t3.x, t3.y), pk2(t3.z, t3.w) };
        *(uint4*)&Srow[64 + sub * 16]     = u0;
        *(uint4*)&Srow[64 + sub * 16 + 8] = u1;
    }
    // x update: one lane per node
    if (lane < 16) {
        const int nn = t * 16 + lane;
        const float cn = fmaxf((float)(rowptr[nn + 1] - rowptr[nn]), 1.0f);
        const float rc = __builtin_amdgcn_rcpf(cn);
        #pragma unroll
        for (int d3 = 0; d3 < 3; ++d3) {
            float tf = sum_f[3 * nn + d3] * rc;
            tf = fminf(fmaxf(tf, -100.0f), 100.0f);
            x[3 * nn + d3] += tf;
        }
    }
    WFENCE();

    // GEMM1: [16x128] @ nW1[128x64] -> SiLU -> alias cols 0..63
    bf16x8 af[4];
    #pragma unroll
    for (int s = 0; s < 4; ++s)
        af[s] = *(const bf16x8*)&S[w][l15][s * 32 + quad * 8];
    WFENCE();
    float nb1v[4], nb2v[4];
    #pragma unroll
    for (int nt = 0; nt < 4; ++nt) {
        nb1v[nt] = nb1[nt * 16 + l15];
        nb2v[nt] = nb2[nt * 16 + l15];
    }
    #pragma unroll
    for (int nt = 0; nt < 4; ++nt) {
        f32x4 a = {0.f, 0.f, 0.f, 0.f};
        #pragma unroll
        for (int s = 0; s < 4; ++s) {
            bf16x8 bf = *(const bf16x8*)(nw1b + ((s * 4 + nt) * 64 + lane) * 8);
            a = __builtin_amdgcn_mfma_f32_16x16x32_bf16(af[s], bf, a, 0, 0, 0);
        }
        #pragma unroll
        for (int rr = 0; rr < 4; ++rr)
            S[w][quad * 4 + rr][nt * 16 + l15] = bfb(silu_f(a[rr] + nb1v[nt]));
    }
    WFENCE();

    // GEMM2: [16x64] @ nW2[64x64] -> h (no act)
    bf16x8 a2[2];
    #pragma unroll
    for (int s = 0; s < 2; ++s)
        a2[s] = *(const bf16x8*)&S[w][l15][s * 32 + quad * 8];
    #pragma unroll
    for (int nt = 0; nt < 4; ++nt) {
        f32x4 m = {0.f, 0.f, 0.f, 0.f};
        #pragma unroll
        for (int s = 0; s < 2; ++s) {
            bf16x8 bf = *(const bf16x8*)(nw2b + ((s * 4 + nt) * 64 + lane) * 8);
            m = __builtin_amdgcn_mfma_f32_16x16x32_bf16(a2[s], bf, m, 0, 0, 0);
        }
        #pragma unroll
        for (int rr = 0; rr < 4; ++rr) {
            const float v = m[rr] + nb2v[nt];
            const size_t nd = (size_t)(t * 16 + quad * 4 + rr) * HH + nt * 16 + l15;
            h[nd] = v;
            hb[nd] = bfb(v);
        }
    }
}

extern "C" void kernel_launch(void* const* d_in, const int* in_sizes, int n_in,
                              void* d_out, int out_size, void* d_ws, size_t ws_size,
                              hipStream_t stream) {
    const float* x_in  = (const float*)d_in[0];
    const float* h_in  = (const float*)d_in[1];
    const int*   row   = (const int*)d_in[2];
    const int*   col   = (const int*)d_in[3];
    const float* efea  = (const float*)d_in[4];
    const float* emb_W = (const float*)d_in[5];
    const float* emb_b = (const float*)d_in[6];
    const float* eW1   = (const float*)d_in[7];
    const float* eb1   = (const float*)d_in[8];
    const float* eW2   = (const float*)d_in[9];
    const float* eb2   = (const float*)d_in[10];
    const float* cW1   = (const float*)d_in[11];
    const float* cb1   = (const float*)d_in[12];
    const float* cW2   = (const float*)d_in[13];
    const float* cb2   = (const float*)d_in[14];
    const float* nW1   = (const float*)d_in[15];
    const float* nb1   = (const float*)d_in[16];
    const float* nW2   = (const float*)d_in[17];
    const float* nb2   = (const float*)d_in[18];

    float* out = (float*)d_out;
    float* xo = out;                 // N*3
    float* ho = out + NN * 3;        // N*64

    // workspace layout (16B-aligned segments first)
    char* wsb = (char*)d_ws;
    float* sum_f = (float*)wsb;                               //    600,000 B
    float* tmsg  = (float*)(wsb + 600000);                    // 12,800,000 B
    unsigned short* efs = (unsigned short*)(wsb + 13400000);  // 12,800,000 B
    unsigned short* hb  = (unsigned short*)(wsb + 26200000);  //  6,400,000 B
    unsigned short* wsW = (unsigned short*)(wsb + 32600000);  //    122,880 B
    int* deg    = (int*)(wsb + 32722880);                     //    200,000 B
    int* rowptr = (int*)(wsb + 32922880);                     //    200,004 B
    int* cur    = (int*)(wsb + 33122884);                     //    200,000 B
    int* rs     = (int*)(wsb + 33322884);                     //  3,200,000 B
    int* cs     = (int*)(wsb + 36522884);                     //  3,200,000 B
    int* bsum   = (int*)(wsb + 39722884);                     //        800 B
    int* boff   = (int*)(wsb + 39723684);                     //        800 B

    // CSR build + sorted-edge materialization (row/col/efea are fixed inputs)
    hipMemsetAsync(deg, 0, NN * sizeof(int), stream);
    hist_kernel<<<MM / 256, 256, 0, stream>>>(row, deg);
    scanA_kernel<<<200, 256, 0, stream>>>(deg, bsum);
    scanB_kernel<<<1, 256, 0, stream>>>(bsum, boff);
    scanC_kernel<<<200, 256, 0, stream>>>(deg, boff, rowptr, cur);
    fill_kernel<<<MM / 256, 256, 0, stream>>>(row, col, efea, cur, rs, cs, efs);

    hipMemcpyAsync(xo, x_in, (size_t)NN * 3 * sizeof(float),
                   hipMemcpyDeviceToDevice, stream);
    prep_embed_kernel<<<240 + (NN * HH) / 256, 256, 0, stream>>>(
        eW1, eW2, cW1, nW1, nW2, wsW, h_in, emb_W, emb_b, ho, hb);

    for (int i = 0; i < 2; ++i) {
        hipMemsetAsync(wsb, 0, 13400000, stream);   // sum_f + tmsg
        const unsigned short* L = wsW + i * 30720;
        edge_mfma_kernel<<<NB_EDGE, 256, 0, stream>>>(
            xo, hb, rs, cs, efs,
            L, L + 10240, L + 14336,
            eb1 + i * 64, eb2 + i * 64, cb1 + i * 64, cW2 + i * 64, cb2 + i,
            sum_f, tmsg);
        node_mfma_kernel<<<(NN / 16 + 3) / 4, 256, 0, stream>>>(
            xo, ho, hb, sum_f, rowptr, tmsg,
            L + 18432, L + 26624, nb1 + i * 64, nb2 + i * 64);
    }
}